// Round 11
// baseline (964.198 us; speedup 1.0000x reference)
//
#include <hip/hip_runtime.h>
#include <cstdint>
#include <cstddef>

// 1/sqrt(1+1e-5)
#define RSQ 0.9999950000374997f
#define LDL 132   // fp32 LDS leading dim (block-0 uz kernel)
#define PITCH 40  // bf16 LDS row pitch (BK=32 + 8 pad) -> <=2-way bank conflicts (free)

typedef __attribute__((ext_vector_type(8))) short bf16x8;
typedef __attribute__((ext_vector_type(4))) float f32x4;

__device__ __forceinline__ float lrelu_f(float x){ return x >= 0.0f ? x : 0.2f * x; }

__device__ __forceinline__ float bf2f(unsigned short u){
  union{unsigned int i; float f;} v; v.i = ((unsigned int)u) << 16; return v.f;
}
__device__ __forceinline__ void splitbf(float x, unsigned short& h, unsigned short& l){
  union{float f; unsigned int i;} a; a.f = x;
  unsigned int r = a.i + 0x7fffu + ((a.i >> 16) & 1u);
  h = (unsigned short)(r >> 16);
  union{unsigned int i; float f;} hf; hf.i = ((unsigned int)h) << 16;
  union{float f; unsigned int i;} b; b.f = x - hf.f;
  unsigned int r2 = b.i + 0x7fffu + ((b.i >> 16) & 1u);
  l = (unsigned short)(r2 >> 16);
}

// monotone float->uint, packed with complemented index for exact lowest-index tie-break
__device__ __forceinline__ unsigned long long packkey(float v, int m){
  union{float f; unsigned int i;} a; a.f = v;
  unsigned int s = a.i;
  unsigned int u = s ^ (((unsigned int)((int)s >> 31)) | 0x80000000u);
  return ((unsigned long long)u << 32) | (unsigned int)(2047 - m);
}

// ascending 64-lane bitonic sort of one u64 key per lane
__device__ __forceinline__ unsigned long long bitonic64_asc(unsigned long long v, int lane){
  #pragma unroll
  for (int k = 2; k <= 64; k <<= 1){
    #pragma unroll
    for (int j = k >> 1; j > 0; j >>= 1){
      unsigned long long o = __shfl_xor(v, j);
      bool up = ((lane & k) == 0);
      bool upper = (lane & j) != 0;
      unsigned long long mx = v > o ? v : o;
      unsigned long long mn = v > o ? o : v;
      v = (upper == up) ? mx : mn;
    }
  }
  return v;
}

// ---------------- small prep kernels ----------------

// x (B,3,N) -> F0 (B*N, 3) fp32
__global__ __launch_bounds__(256) void k_transpose(const float* __restrict__ x, float* __restrict__ F0){
  int t = blockIdx.x * 256 + threadIdx.x;
  if (t >= 16*3*2048) return;
  int n = t & 2047;
  int bc = t >> 11;
  int c = bc % 3, b = bc / 3;
  F0[(size_t)(b*2048 + n)*3 + c] = x[t];
}

// split a plain fp32 array into hi/lo bf16 planes
__global__ __launch_bounds__(256) void k_split_plain(const float* __restrict__ W, int n,
    unsigned short* __restrict__ H, unsigned short* __restrict__ L){
  int t = blockIdx.x * 256 + threadIdx.x;
  if (t >= n) return;
  unsigned short h, l; splitbf(W[t], h, l);
  H[t] = h; L[t] = l;
}

// build combined UZ weights: rows [0,O) = W[:, :C]; rows [O,2O) = W[:, C:] - W[:, :C]; split hi/lo
__global__ __launch_bounds__(256) void k_make_wuz(const float* __restrict__ W, int O, int cshift,
    unsigned short* __restrict__ WH, unsigned short* __restrict__ WL){
  int C = 1 << cshift;
  int n = 2*O*C;
  int t = blockIdx.x * 256 + threadIdx.x;
  if (t >= n) return;
  int g = t >> cshift, c = t & (C - 1);
  int C2 = 2*C;
  float w;
  if (g < O) w = W[(size_t)g*C2 + c];
  else       w = W[(size_t)(g-O)*C2 + C + c] - W[(size_t)(g-O)*C2 + c];
  unsigned short h, l; splitbf(w, h, l);
  WH[t] = h; WL[t] = l;
}

// row norms from hi/lo planes (slice c0..c0+C of 512-wide rows)
__global__ __launch_bounds__(256) void k_norms_bf(const unsigned short* __restrict__ H,
    const unsigned short* __restrict__ L, int c0, int C, float* __restrict__ xx){
  int row = blockIdx.x * 256 + threadIdx.x;
  const unsigned short* h = H + (size_t)row*512 + c0;
  const unsigned short* l = L + (size_t)row*512 + c0;
  float a = 0.f;
  for (int c = 0; c < C; c += 8){
    bf16x8 vh = *(const bf16x8*)(h + c);
    bf16x8 vl = *(const bf16x8*)(l + c);
    #pragma unroll
    for (int j = 0; j < 8; ++j){
      float f = bf2f((unsigned short)vh[j]) + bf2f((unsigned short)vl[j]);
      a += f*f;
    }
  }
  xx[row] = a;
}

// ---------------- MFMA GEMM core (128x128 tile, BK=32, split-bf16 3-product) ----------------

__device__ __forceinline__ void stage_pair(unsigned short* dH, unsigned short* dL,
    const unsigned short* sH, const unsigned short* sL, int rowBase, int ld, int kOff, int tid){
  #pragma unroll
  for (int i = 0; i < 2; ++i){
    int q = tid + 256*i; int r = q >> 2; int kq = (q & 3) * 8;
    size_t go = (size_t)(rowBase + r)*ld + kOff + kq;
    *(bf16x8*)&dH[r*PITCH + kq] = *(const bf16x8*)(sH + go);
    *(bf16x8*)&dL[r*PITCH + kq] = *(const bf16x8*)(sL + go);
  }
}

__device__ __forceinline__ void mfma_step(const unsigned short* sAh, const unsigned short* sAl,
    const unsigned short* sBh, const unsigned short* sBl, int wm, int wn, int lane, f32x4 acc[4][4]){
  bf16x8 ah[4], al[4], bh[4], bl[4];
  int ko = (lane >> 4) * 8, li = lane & 15;
  #pragma unroll
  for (int i = 0; i < 4; ++i){
    ah[i] = *(const bf16x8*)&sAh[(wm + i*16 + li)*PITCH + ko];
    al[i] = *(const bf16x8*)&sAl[(wm + i*16 + li)*PITCH + ko];
    bh[i] = *(const bf16x8*)&sBh[(wn + i*16 + li)*PITCH + ko];
    bl[i] = *(const bf16x8*)&sBl[(wn + i*16 + li)*PITCH + ko];
  }
  #pragma unroll
  for (int mi = 0; mi < 4; ++mi){
    #pragma unroll
    for (int ni = 0; ni < 4; ++ni){
      acc[mi][ni] = __builtin_amdgcn_mfma_f32_16x16x32_bf16(ah[mi], bh[ni], acc[mi][ni], 0,0,0);
      acc[mi][ni] = __builtin_amdgcn_mfma_f32_16x16x32_bf16(ah[mi], bl[ni], acc[mi][ni], 0,0,0);
      acc[mi][ni] = __builtin_amdgcn_mfma_f32_16x16x32_bf16(al[mi], bh[ni], acc[mi][ni], 0,0,0);
    }
  }
}

// symmetric dist: only upper-triangle tile pairs (ti<=tj); off-diag mirrored via LDS transpose.
// D[z][n][m] = 2*<F[n],F[m]> - xx[n] - xx[m]; value symmetric -> mirror is bit-identical.
__global__ __launch_bounds__(256) void k_dist_sym(const unsigned short* __restrict__ H,
    const unsigned short* __restrict__ L, int C, const float* __restrict__ xx,
    float* __restrict__ D, int b0){
  __shared__ unsigned short sstage[4*128*PITCH];   // 40960 B; also reused as 2x 64x65 float tiles
  unsigned short* sAh = sstage;
  unsigned short* sAl = sstage + 128*PITCH;
  unsigned short* sBh = sstage + 2*128*PITCH;
  unsigned short* sBl = sstage + 3*128*PITCH;
  float* tbuf = (float*)sstage;
  int rem = blockIdx.x;            // triangular decode: 136 pairs
  int ti = 0;
  while (rem >= 16 - ti){ rem -= 16 - ti; ++ti; }
  int tj = ti + rem;
  int b = b0 + blockIdx.y;
  int nb = ti*128, mb = tj*128;
  int rowA0 = b*2048 + nb, rowB0 = b*2048 + mb;
  int tid = threadIdx.x, lane = tid & 63, w = tid >> 6;
  int wm = (w >> 1) * 64, wn = (w & 1) * 64;
  f32x4 acc[4][4];
  #pragma unroll
  for (int i = 0; i < 4; ++i)
    #pragma unroll
    for (int j = 0; j < 4; ++j){ f32x4 z = {0.f,0.f,0.f,0.f}; acc[i][j] = z; }
  for (int kk = 0; kk < C; kk += 32){
    __syncthreads();
    stage_pair(sAh, sAl, H, L, rowA0, 512, kk, tid);
    stage_pair(sBh, sBl, H, L, rowB0, 512, kk, tid);
    __syncthreads();
    mfma_step(sAh, sAl, sBh, sBl, wm, wn, lane, acc);
  }
  int li = lane & 15, lq = lane >> 4;
  float xm[4];
  #pragma unroll
  for (int ni = 0; ni < 4; ++ni) xm[ni] = xx[rowB0 + wn + ni*16 + li];
  // finalize values in-place, then direct write
  #pragma unroll
  for (int mi = 0; mi < 4; ++mi){
    #pragma unroll
    for (int v = 0; v < 4; ++v){
      int row = wm + mi*16 + lq*4 + v;
      float xn = xx[rowA0 + row];
      size_t base = ((size_t)(blockIdx.y*2048 + nb + row))*2048 + mb;
      #pragma unroll
      for (int ni = 0; ni < 4; ++ni){
        float fv = 2.f*acc[mi][ni][v] - xn - xm[ni];
        acc[mi][ni][v] = fv;
        D[base + wn + ni*16 + li] = fv;
      }
    }
  }
  if (ti != tj){
    // mirror: per-wave 64x65 LDS transpose, two wave-pair passes (LDS budget)
    float* tb = tbuf + (w & 1) * (64*65);
    #pragma unroll
    for (int pass = 0; pass < 2; ++pass){
      __syncthreads();
      if ((w >> 1) == pass){
        #pragma unroll
        for (int mi = 0; mi < 4; ++mi)
          #pragma unroll
          for (int ni = 0; ni < 4; ++ni)
            #pragma unroll
            for (int v = 0; v < 4; ++v)
              tb[(mi*16 + lq*4 + v)*65 + ni*16 + li] = acc[mi][ni][v];
        // same-wave LDS write->read: HW-ordered; no barrier needed
        for (int r2 = 0; r2 < 64; ++r2){
          size_t rb = ((size_t)(blockIdx.y*2048 + mb + wn + r2))*2048 + nb + wm;
          D[rb + lane] = tb[lane*65 + r2];
        }
      }
    }
  }
}

// uz: UZ[row][g] = <F[row], WUZ[g]> (fp32 out), F slice ld 512, WUZ ld C
__global__ __launch_bounds__(256) void k_uz_mfma(const unsigned short* __restrict__ H,
    const unsigned short* __restrict__ L, int C,
    const unsigned short* __restrict__ WH, const unsigned short* __restrict__ WL,
    int N2, float* __restrict__ UZ){
  __shared__ unsigned short sAh[128*PITCH], sAl[128*PITCH], sBh[128*PITCH], sBl[128*PITCH];
  int rows0 = blockIdx.x * 128;
  int ob = blockIdx.y * 128;
  int tid = threadIdx.x, lane = tid & 63, w = tid >> 6;
  int wm = (w >> 1) * 64, wn = (w & 1) * 64;
  f32x4 acc[4][4];
  #pragma unroll
  for (int i = 0; i < 4; ++i)
    #pragma unroll
    for (int j = 0; j < 4; ++j){ f32x4 z = {0.f,0.f,0.f,0.f}; acc[i][j] = z; }
  for (int kk = 0; kk < C; kk += 32){
    __syncthreads();
    stage_pair(sAh, sAl, H, L, rows0, 512, kk, tid);
    stage_pair(sBh, sBl, WH, WL, ob, C, kk, tid);
    __syncthreads();
    mfma_step(sAh, sAl, sBh, sBl, wm, wn, lane, acc);
  }
  int li = lane & 15, lq = lane >> 4;
  #pragma unroll
  for (int mi = 0; mi < 4; ++mi){
    #pragma unroll
    for (int v = 0; v < 4; ++v){
      int row = rows0 + wm + mi*16 + lq*4 + v;
      size_t base = (size_t)row * N2 + ob;
      #pragma unroll
      for (int ni = 0; ni < 4; ++ni) UZ[base + wn + ni*16 + li] = acc[mi][ni][v];
    }
  }
}

// conv5: A = XCH/XCL (32768x512), B = W5 split (1024x512); fused bn/lrelu + max/sum over 128-pt tile
__global__ __launch_bounds__(256) void k_conv5_mfma(const unsigned short* __restrict__ XH,
    const unsigned short* __restrict__ XL, const unsigned short* __restrict__ WH,
    const unsigned short* __restrict__ WL, const float* __restrict__ g5, const float* __restrict__ b5,
    float* __restrict__ pmax, float* __restrict__ psum){
  __shared__ unsigned short sAh[128*PITCH], sAl[128*PITCH], sBh[128*PITCH], sBl[128*PITCH];
  __shared__ float redm[2][128];
  __shared__ float reds[2][128];
  int bx = blockIdx.x;
  int b = bx >> 4, nt = bx & 15;
  int ob = blockIdx.y * 128;
  int rowA0 = b*2048 + nt*128;
  int tid = threadIdx.x, lane = tid & 63, w = tid >> 6;
  int wm = (w >> 1) * 64, wn = (w & 1) * 64, wy = w >> 1, wx = w & 1;
  f32x4 acc[4][4];
  #pragma unroll
  for (int i = 0; i < 4; ++i)
    #pragma unroll
    for (int j = 0; j < 4; ++j){ f32x4 z = {0.f,0.f,0.f,0.f}; acc[i][j] = z; }
  for (int kk = 0; kk < 512; kk += 32){
    __syncthreads();
    stage_pair(sAh, sAl, XH, XL, rowA0, 512, kk, tid);
    stage_pair(sBh, sBl, WH, WL, ob, 512, kk, tid);
    __syncthreads();
    mfma_step(sAh, sAl, sBh, sBl, wm, wn, lane, acc);
  }
  int li = lane & 15;
  #pragma unroll
  for (int ni = 0; ni < 4; ++ni){
    int c = ob + wn + ni*16 + li;
    float s = g5[c] * RSQ, bb = b5[c];
    float m = -INFINITY, sm = 0.f;
    #pragma unroll
    for (int mi = 0; mi < 4; ++mi){
      #pragma unroll
      for (int v = 0; v < 4; ++v){
        float y = lrelu_f(s*acc[mi][ni][v] + bb);
        m = fmaxf(m, y);
        sm += y;
      }
    }
    m = fmaxf(m, __shfl_xor(m, 16)); m = fmaxf(m, __shfl_xor(m, 32));
    sm += __shfl_xor(sm, 16); sm += __shfl_xor(sm, 32);
    if (lane < 16){
      redm[wy][wx*64 + ni*16 + li] = m;
      reds[wy][wx*64 + ni*16 + li] = sm;
    }
  }
  __syncthreads();
  if (tid < 128){
    float m = fmaxf(redm[0][tid], redm[1][tid]);
    float s = reds[0][tid] + reds[1][tid];
    size_t pi = (size_t)(b*16 + nt)*1024 + ob + tid;
    pmax[pi] = m;
    psum[pi] = s;
  }
}

// ---------------- fp32 kernels for block 0 (C=3) ----------------

__global__ __launch_bounds__(256) void k_dist3(const float* __restrict__ F0, float* __restrict__ D, int b0){
  __shared__ float sa[3][128];
  __shared__ float sb[3][128];
  int b = b0 + blockIdx.z;
  int nb = blockIdx.y * 128, mb = blockIdx.x * 128;
  int tid = threadIdx.x, tx = tid & 15, ty = tid >> 4;
  if (tid < 128){
    int r = tid;
    const float* p = F0 + (size_t)(b*2048 + nb + r)*3;
    sa[0][r] = p[0]; sa[1][r] = p[1]; sa[2][r] = p[2];
  } else {
    int r = tid - 128;
    const float* p = F0 + (size_t)(b*2048 + mb + r)*3;
    sb[0][r] = p[0]; sb[1][r] = p[1]; sb[2][r] = p[2];
  }
  __syncthreads();
  float ax[8], ay[8], az[8], bx[8], by[8], bz[8];
  #pragma unroll
  for (int i=0;i<8;i++){
    int ri = (i<4) ? 4*ty+i : 64 + 4*ty + (i-4);
    ax[i] = sa[0][ri]; ay[i] = sa[1][ri]; az[i] = sa[2][ri];
    int cj = (i<4) ? 4*tx+i : 64 + 4*tx + (i-4);
    bx[i] = sb[0][cj]; by[i] = sb[1][cj]; bz[i] = sb[2][cj];
  }
  #pragma unroll
  for (int i=0;i<8;i++){
    int ri = (i<4) ? 4*ty+i : 64 + 4*ty + (i-4);
    size_t base = ((size_t)(blockIdx.z*2048 + nb + ri))*2048 + mb;
    float v[8];
    #pragma unroll
    for (int j=0;j<8;j++){
      float dx = ax[i]-bx[j], dy = ay[i]-by[j], dz = az[i]-bz[j];
      v[j] = -(dx*dx + dy*dy + dz*dz);
    }
    *(float4*)&D[base + 4*tx]      = make_float4(v[0],v[1],v[2],v[3]);
    *(float4*)&D[base + 64 + 4*tx] = make_float4(v[4],v[5],v[6],v[7]);
  }
}

#define GEMM_STEP(KK) { \
      float a[8], wv_[8]; \
      *(float4*)&a[0] = *(const float4*)&As[(KK)*LDL + 4*ty]; \
      *(float4*)&a[4] = *(const float4*)&As[(KK)*LDL + 64 + 4*ty]; \
      *(float4*)&wv_[0] = *(const float4*)&Bs[(KK)*LDL + 4*tx]; \
      *(float4*)&wv_[4] = *(const float4*)&Bs[(KK)*LDL + 64 + 4*tx]; \
      _Pragma("unroll") \
      for (int i_ = 0; i_ < 8; ++i_){ \
        _Pragma("unroll") \
        for (int j_ = 0; j_ < 8; ++j_) acc[i_][j_] += a[i_]*wv_[j_]; \
      } }

// fp32 uz for block 0 (C=3): UZ[row][0:O]=F.Wd^T, UZ[row][O:2O]=F.(Wc-Wd)^T
__global__ __launch_bounds__(256) void k_uz(const float* __restrict__ F, int ldF, int C,
    const float* __restrict__ W, int O, float* __restrict__ UZ){
  __shared__ float As[32*LDL];
  __shared__ float Bs[32*LDL];
  int N2 = 2*O, C2 = 2*C;
  int rows0 = blockIdx.x * 128;
  int ob = blockIdx.y * 128;
  int tid = threadIdx.x, tx = tid & 15, ty = tid >> 4;
  float acc[8][8] = {};
  for (int cc = 0; cc < C; cc += 32){
    int kc = C - cc; if (kc > 32) kc = 32;
    __syncthreads();
    for (int t = tid; t < 128*32; t += 256){
      int r = t >> 5, k = t & 31;
      if (k < kc){
        As[k*LDL + r] = F[(size_t)(rows0 + r)*ldF + cc + k];
        int g = ob + r; float wv;
        if (g < O) wv = W[(size_t)g*C2 + cc + k];
        else       wv = W[(size_t)(g-O)*C2 + C + cc + k] - W[(size_t)(g-O)*C2 + cc + k];
        Bs[k*LDL + r] = wv;
      }
    }
    __syncthreads();
    for (int k = 0; k < kc; ++k) GEMM_STEP(k)
  }
  #pragma unroll
  for (int i=0;i<8;i++){
    int ri = (i<4) ? 4*ty+i : 64 + 4*ty + (i-4);
    size_t base = (size_t)(rows0 + ri)*N2 + ob;
    *(float4*)&UZ[base + 4*tx]      = make_float4(acc[i][0],acc[i][1],acc[i][2],acc[i][3]);
    *(float4*)&UZ[base + 64 + 4*tx] = make_float4(acc[i][4],acc[i][5],acc[i][6],acc[i][7]);
  }
}

// ---------------- kNN select / aggregate / pool / fc ----------------

// top-20 per row: threshold (20th-largest lane-max via bitonic) + ballot-compaction + final bitonic.
// float4 row loads; lane owns indices {j*256 + lane*4 + t}. Threshold bound is partition-independent.
__global__ __launch_bounds__(256) void k_knn_select(const float* __restrict__ D, int* __restrict__ idxo, int b0){
  __shared__ unsigned long long cand[4][64];
  int g = blockIdx.y; int b = b0 + g;
  int w = threadIdx.x >> 6, lane = threadIdx.x & 63;
  int r = blockIdx.x*4 + w;
  const float* Drow = D + ((size_t)(g*2048 + r))*2048;
  float vals[32];
  unsigned long long kmax = 0ull;
  #pragma unroll
  for (int j=0;j<8;j++){
    float4 v4 = *(const float4*)(Drow + j*256 + lane*4);
    int m0 = j*256 + lane*4;
    vals[j*4+0]=v4.x; vals[j*4+1]=v4.y; vals[j*4+2]=v4.z; vals[j*4+3]=v4.w;
    unsigned long long e;
    e = packkey(v4.x, m0+0); if (e > kmax) kmax = e;
    e = packkey(v4.y, m0+1); if (e > kmax) kmax = e;
    e = packkey(v4.z, m0+2); if (e > kmax) kmax = e;
    e = packkey(v4.w, m0+3); if (e > kmax) kmax = e;
  }
  // 20th largest of the 64 lane-maxes (ascending sort -> index 44); provable lower bound on true t20
  unsigned long long srt = bitonic64_asc(kmax, lane);
  unsigned long long t = __shfl(srt, 44);
  // compact keys >= t
  unsigned long long ltmask = (1ull << lane) - 1ull;
  int base = 0;
  #pragma unroll
  for (int s=0;s<32;s++){
    int m = (s >> 2)*256 + lane*4 + (s & 3);
    unsigned long long ke = packkey(vals[s], m);
    bool pred = ke >= t;
    unsigned long long mask = __ballot(pred);
    int pos = base + __popcll(mask & ltmask);
    if (pred && pos < 64) cand[w][pos] = ke;
    base += __popcll(mask);
  }
  int* op = idxo + (size_t)(b*2048 + r)*20;
  if (base <= 64){
    unsigned long long ck = (lane < base) ? cand[w][lane] : 0ull;
    ck = bitonic64_asc(ck, lane);
    if (lane >= 44) op[63 - lane] = 2047 - (int)(ck & 0xFFFFFFFFull);
  } else {
    // fallback: lazy iterative argmax (rare, correctness guarantee)
    unsigned long long k1 = 0ull, k2 = 0ull;
    #pragma unroll
    for (int s=0;s<32;s++){
      int m = (s >> 2)*256 + lane*4 + (s & 3);
      unsigned long long ke = packkey(vals[s], m);
      if (ke > k1){ k2 = k1; k1 = ke; }
      else if (ke > k2){ k2 = ke; }
    }
    unsigned int removed = 0u;
    for (int it = 0; it < 20; ++it){
      unsigned long long km = k1;
      #pragma unroll
      for (int off = 1; off < 64; off <<= 1){
        unsigned long long o2 = __shfl_xor(km, off);
        if (o2 > km) km = o2;
      }
      int bi = 2047 - (int)(km & 0xFFFFFFFFull);
      if (lane == 0) op[it] = bi;
      if (km == k1){
        removed |= 1u << (((bi >> 8) << 2) | (bi & 3));
        if (k2 != 0ull){ k1 = k2; k2 = 0ull; }
        else {
          unsigned long long b1 = 0ull, b2 = 0ull;
          #pragma unroll
          for (int s=0;s<32;s++){
            if (!((removed >> s) & 1u)){
              int m = (s >> 2)*256 + lane*4 + (s & 3);
              unsigned long long ke = packkey(vals[s], m);
              if (ke > b1){ b2 = b1; b1 = ke; }
              else if (ke > b2){ b2 = ke; }
            }
          }
          k1 = b1; k2 = b2;
        }
      }
    }
  }
}

// out(point,o..o+3) = lrelu(bn( max_j UZ[nbr_j][o] + UZ[point][O+o] )) -> hi/lo bf16 planes
// blockIdx swizzled so batch == (blockIdx & 7)-affine -> per-XCD L2 sees ~2 batch slabs
__global__ __launch_bounds__(256) void k_aggregate(const float* __restrict__ UZ,
    const int* __restrict__ idx, const float* __restrict__ gam, const float* __restrict__ bet,
    int oshift, unsigned short* __restrict__ outH, unsigned short* __restrict__ outL){
  int O = 1 << oshift;
  int ogshift = oshift - 2;           // float4 groups per point = O/4
  int tid = threadIdx.x;
  // XCD batch-locality swizzle: bijection on [0, gridDim.x)
  int NBB = gridDim.x >> 4;           // blocks per batch
  int g = blockIdx.x;
  int q = g >> 3, xq = g & 7;
  int hi = (q >= NBB) ? 1 : 0;
  int within = q - NBB*hi;
  int batch = xq + 8*hi;
  int pblock = batch * NBB + within;
  int point = pblock * (256 >> ogshift) + (tid >> ogshift);
  int o = (tid & ((O >> 2) - 1)) << 2;
  int N2 = 2*O;
  int b = point >> 11;
  const int* ip = idx + (size_t)point * 20;
  float4 mv = make_float4(-INFINITY,-INFINITY,-INFINITY,-INFINITY);
  #pragma unroll
  for (int j = 0; j < 20; ++j){
    int m = ip[j];
    float4 v = *(const float4*)(UZ + (size_t)((b << 11) + m)*N2 + o);
    mv.x = fmaxf(mv.x, v.x); mv.y = fmaxf(mv.y, v.y);
    mv.z = fmaxf(mv.z, v.z); mv.w = fmaxf(mv.w, v.w);
  }
  float4 z = *(const float4*)(UZ + (size_t)point*N2 + O + o);
  float s0 = gam[o+0]*RSQ, s1 = gam[o+1]*RSQ, s2 = gam[o+2]*RSQ, s3 = gam[o+3]*RSQ;
  float y0 = lrelu_f(s0*(mv.x + z.x) + bet[o+0]);
  float y1 = lrelu_f(s1*(mv.y + z.y) + bet[o+1]);
  float y2 = lrelu_f(s2*(mv.z + z.z) + bet[o+2]);
  float y3 = lrelu_f(s3*(mv.w + z.w) + bet[o+3]);
  ushort4 hh, ll;
  splitbf(y0, hh.x, ll.x); splitbf(y1, hh.y, ll.y);
  splitbf(y2, hh.z, ll.z); splitbf(y3, hh.w, ll.w);
  *(ushort4*)&outH[(size_t)point*512 + o] = hh;
  *(ushort4*)&outL[(size_t)point*512 + o] = ll;
}

__global__ __launch_bounds__(256) void k_pool(const float* __restrict__ pmax, const float* __restrict__ psum,
    float* __restrict__ p){
  int t = blockIdx.x * 256 + threadIdx.x; // 16384
  int b = t >> 10, o = t & 1023;
  float m = -INFINITY, s = 0.f;
  for (int nt = 0; nt < 16; ++nt){
    size_t pi = (size_t)(b*16 + nt)*1024 + o;
    m = fmaxf(m, pmax[pi]);
    s += psum[pi];
  }
  p[(size_t)b*2048 + o] = m;
  p[(size_t)b*2048 + 1024 + o] = s * (1.f/2048.f);
}

// ---------- grid-parallel FC head ----------
__global__ __launch_bounds__(256) void k_fc1(const float* __restrict__ p, const float* __restrict__ L1w,
    const float* __restrict__ g6, const float* __restrict__ b6, float* __restrict__ h1){
  int o = blockIdx.x;
  int tid = threadIdx.x, lane = tid & 63, w = tid >> 6;
  int k0 = w*512 + lane*8;
  const float4* wp = (const float4*)(L1w + (size_t)o*2048 + k0);
  float4 w0 = wp[0], w1 = wp[1];
  __shared__ float part[4][16];
  for (int b = 0; b < 16; ++b){
    const float4* pp = (const float4*)(p + (size_t)b*2048 + k0);
    float4 p0 = pp[0], p1 = pp[1];
    float a = p0.x*w0.x + p0.y*w0.y + p0.z*w0.z + p0.w*w0.w
            + p1.x*w1.x + p1.y*w1.y + p1.z*w1.z + p1.w*w1.w;
    #pragma unroll
    for (int off = 32; off >= 1; off >>= 1) a += __shfl_down(a, off);
    if (lane == 0) part[w][b] = a;
  }
  __syncthreads();
  if (tid < 16){
    float a = part[0][tid] + part[1][tid] + part[2][tid] + part[3][tid];
    h1[(size_t)tid*512 + o] = lrelu_f(g6[o]*RSQ*a + b6[o]);
  }
}

__global__ __launch_bounds__(256) void k_fc2(const float* __restrict__ h1, const float* __restrict__ L2w,
    const float* __restrict__ L2b, const float* __restrict__ g7, const float* __restrict__ b7,
    float* __restrict__ h2){
  int o = blockIdx.x;
  int tid = threadIdx.x, lane = tid & 63, w = tid >> 6;
  int k0 = w*128 + lane*2;
  float2 wv = *(const float2*)(L2w + (size_t)o*512 + k0);
  __shared__ float part[4][16];
  for (int b = 0; b < 16; ++b){
    float2 hv = *(const float2*)(h1 + (size_t)b*512 + k0);
    float a = hv.x*wv.x + hv.y*wv.y;
    #pragma unroll
    for (int off = 32; off >= 1; off >>= 1) a += __shfl_down(a, off);
    if (lane == 0) part[w][b] = a;
  }
  __syncthreads();
  if (tid < 16){
    float a = part[0][tid] + part[1][tid] + part[2][tid] + part[3][tid] + L2b[o];
    h2[(size_t)tid*256 + o] = lrelu_f(g7[o]*RSQ*a + b7[o]);
  }
}

__global__ __launch_bounds__(256) void k_fc3(const float* __restrict__ h2, const float* __restrict__ L3w,
    const float* __restrict__ L3b, float* __restrict__ out){
  int o = blockIdx.x;
  int tid = threadIdx.x, lane = tid & 63, w = tid >> 6;
  int k0 = w*64 + lane;
  float wv = L3w[(size_t)o*256 + k0];
  __shared__ float part[4][16];
  for (int b = 0; b < 16; ++b){
    float a = h2[(size_t)b*256 + k0] * wv;
    #pragma unroll
    for (int off = 32; off >= 1; off >>= 1) a += __shfl_down(a, off);
    if (lane == 0) part[w][b] = a;
  }
  __syncthreads();
  if (tid < 16){
    float a = part[0][tid] + part[1][tid] + part[2][tid] + part[3][tid] + L3b[o];
    out[(size_t)tid*40 + o] = a;
  }
}

extern "C" void kernel_launch(void* const* d_in, const int* in_sizes, int n_in,
                              void* d_out, int out_size, void* d_ws, size_t ws_size,
                              hipStream_t stream) {
  (void)in_sizes; (void)n_in; (void)out_size;
  const float* x   = (const float*)d_in[0];
  const float* W1  = (const float*)d_in[1];
  const float* W2  = (const float*)d_in[2];
  const float* W3  = (const float*)d_in[3];
  const float* W4  = (const float*)d_in[4];
  const float* W5  = (const float*)d_in[5];
  const float* g1  = (const float*)d_in[6];   const float* b1  = (const float*)d_in[7];
  const float* g2  = (const float*)d_in[8];   const float* b2  = (const float*)d_in[9];
  const float* g3  = (const float*)d_in[10];  const float* b3  = (const float*)d_in[11];
  const float* g4  = (const float*)d_in[12];  const float* b4  = (const float*)d_in[13];
  const float* g5  = (const float*)d_in[14];  const float* b5  = (const float*)d_in[15];
  const float* g6  = (const float*)d_in[16];  const float* b6  = (const float*)d_in[17];
  const float* g7  = (const float*)d_in[18];  const float* b7  = (const float*)d_in[19];
  const float* L1w = (const float*)d_in[20];
  const float* L2w = (const float*)d_in[21];  const float* L2b = (const float*)d_in[22];
  const float* L3w = (const float*)d_in[23];  const float* L3b = (const float*)d_in[24];
  float* out = (float*)d_out;

  char* ws = (char*)d_ws;
  size_t off = 0;
  auto alloc = [&](size_t nbytes) -> void* {
    void* pp = (void*)(ws + off);
    off += (nbytes + 255) & ~(size_t)255;
    return pp;
  };
  float*          F0   = (float*)alloc(98304ull * 4);
  unsigned short* XCH  = (unsigned short*)alloc(16777216ull * 2);
  unsigned short* XCL  = (unsigned short*)alloc(16777216ull * 2);
  float*          UZ   = (float*)alloc(16777216ull * 4);
  float*          XX   = (float*)alloc(32768ull * 4);
  int*            IDX  = (int*)alloc(655360ull * 4);
  float*          PM   = (float*)alloc(262144ull * 4);
  float*          PS   = (float*)alloc(262144ull * 4);
  float*          P    = (float*)alloc(32768ull * 4);
  float*          H1   = (float*)alloc(8192ull * 4);
  float*          H2   = (float*)alloc(4096ull * 4);
  unsigned short* W5H  = (unsigned short*)alloc(524288ull * 2);
  unsigned short* W5L  = (unsigned short*)alloc(524288ull * 2);
  unsigned short* WUZH = (unsigned short*)alloc(65536ull * 2);
  unsigned short* WUZL = (unsigned short*)alloc(65536ull * 2);
  const size_t dbytes = 2048ull * 2048ull * 4ull;           // one batch of D
  size_t rem = (ws_size > off) ? (ws_size - off) : 0;
  int G = (int)(rem / dbytes);
  if (G > 8) G = 8;   // keep D chunk (<=128 MB) L3-resident between dist write and knn read
  if (G < 1) G = 1;
  float* Dbuf = (float*)(ws + off);

  k_transpose<<<dim3(384), dim3(256), 0, stream>>>(x, F0);
  k_split_plain<<<dim3(2048), dim3(256), 0, stream>>>(W5, 524288, W5H, W5L);

  struct Blk { int c0; int C; int cshift; const float* W; const float* g; const float* bb; int O; int oshift; int c0out; };
  Blk cfg[4] = {
    { 0,   3,   0, W1, g1, b1, 64,  6, 0   },   // block 0 special (fp32 path)
    { 0,   64,  6, W2, g2, b2, 64,  6, 64  },
    { 64,  64,  6, W3, g3, b3, 128, 7, 128 },
    { 128, 128, 7, W4, g4, b4, 256, 8, 256 },
  };

  for (int blk = 0; blk < 4; ++blk){
    const Blk& c = cfg[blk];
    if (blk > 0){
      k_make_wuz<<<dim3((2*c.O*c.C + 255)/256), dim3(256), 0, stream>>>(c.W, c.O, c.cshift, WUZH, WUZL);
      k_norms_bf<<<dim3(128), dim3(256), 0, stream>>>(XCH, XCL, c.c0, c.C, XX);
    }
    for (int b0 = 0; b0 < 16; b0 += G){
      int Gc = 16 - b0; if (Gc > G) Gc = G;
      if (blk == 0)
        k_dist3<<<dim3(16, 16, Gc), dim3(256), 0, stream>>>(F0, Dbuf, b0);
      else
        k_dist_sym<<<dim3(136, Gc), dim3(256), 0, stream>>>(XCH + c.c0, XCL + c.c0, c.C, XX, Dbuf, b0);
      k_knn_select<<<dim3(512, Gc), dim3(256), 0, stream>>>(Dbuf, IDX, b0);
    }
    if (blk == 0)
      k_uz<<<dim3(256, 1), dim3(256), 0, stream>>>(F0, 3, 3, c.W, c.O, UZ);
    else
      k_uz_mfma<<<dim3(256, (2*c.O)/128), dim3(256), 0, stream>>>(XCH + c.c0, XCL + c.c0, c.C, WUZH, WUZL, 2*c.O, UZ);
    k_aggregate<<<dim3(32768 >> (8 - (c.oshift - 2))), dim3(256), 0, stream>>>(UZ, IDX, c.g, c.bb, c.oshift,
                                                                         XCH + c.c0out, XCL + c.c0out);
  }

  k_conv5_mfma<<<dim3(256, 8), dim3(256), 0, stream>>>(XCH, XCL, W5H, W5L, g5, b5, PM, PS);
  k_pool<<<dim3(64), dim3(256), 0, stream>>>(PM, PS, P);
  k_fc1<<<dim3(512), dim3(256), 0, stream>>>(P, L1w, g6, b6, H1);
  k_fc2<<<dim3(256), dim3(256), 0, stream>>>(H1, L2w, L2b, g7, b7, H2);
  k_fc3<<<dim3(40),  dim3(256), 0, stream>>>(H2, L3w, L3b, out);
}

// Round 12
// 911.083 us; speedup vs baseline: 1.0583x; 1.0583x over previous
//
#include <hip/hip_runtime.h>
#include <cstdint>
#include <cstddef>

// 1/sqrt(1+1e-5)
#define RSQ 0.9999950000374997f
#define LDL 132   // fp32 LDS leading dim (block-0 uz kernel)
#define PITCH 40  // bf16 LDS row pitch (BK=32 + 8 pad) -> <=2-way bank conflicts (free)

typedef __attribute__((ext_vector_type(8))) short bf16x8;
typedef __attribute__((ext_vector_type(4))) float f32x4;

__device__ __forceinline__ float lrelu_f(float x){ return x >= 0.0f ? x : 0.2f * x; }

__device__ __forceinline__ float bf2f(unsigned short u){
  union{unsigned int i; float f;} v; v.i = ((unsigned int)u) << 16; return v.f;
}
__device__ __forceinline__ void splitbf(float x, unsigned short& h, unsigned short& l){
  union{float f; unsigned int i;} a; a.f = x;
  unsigned int r = a.i + 0x7fffu + ((a.i >> 16) & 1u);
  h = (unsigned short)(r >> 16);
  union{unsigned int i; float f;} hf; hf.i = ((unsigned int)h) << 16;
  union{float f; unsigned int i;} b; b.f = x - hf.f;
  unsigned int r2 = b.i + 0x7fffu + ((b.i >> 16) & 1u);
  l = (unsigned short)(r2 >> 16);
}

// monotone float->uint, packed with complemented index for exact lowest-index tie-break
__device__ __forceinline__ unsigned long long packkey(float v, int m){
  union{float f; unsigned int i;} a; a.f = v;
  unsigned int s = a.i;
  unsigned int u = s ^ (((unsigned int)((int)s >> 31)) | 0x80000000u);
  return ((unsigned long long)u << 32) | (unsigned int)(2047 - m);
}

// ascending 64-lane bitonic sort of one u64 key per lane
__device__ __forceinline__ unsigned long long bitonic64_asc(unsigned long long v, int lane){
  #pragma unroll
  for (int k = 2; k <= 64; k <<= 1){
    #pragma unroll
    for (int j = k >> 1; j > 0; j >>= 1){
      unsigned long long o = __shfl_xor(v, j);
      bool up = ((lane & k) == 0);
      bool upper = (lane & j) != 0;
      unsigned long long mx = v > o ? v : o;
      unsigned long long mn = v > o ? o : v;
      v = (upper == up) ? mx : mn;
    }
  }
  return v;
}

// ---------------- small prep kernels ----------------

// x (B,3,N) -> F0 (B*N, 3) fp32
__global__ __launch_bounds__(256) void k_transpose(const float* __restrict__ x, float* __restrict__ F0){
  int t = blockIdx.x * 256 + threadIdx.x;
  if (t >= 16*3*2048) return;
  int n = t & 2047;
  int bc = t >> 11;
  int c = bc % 3, b = bc / 3;
  F0[(size_t)(b*2048 + n)*3 + c] = x[t];
}

// split a plain fp32 array into hi/lo bf16 planes
__global__ __launch_bounds__(256) void k_split_plain(const float* __restrict__ W, int n,
    unsigned short* __restrict__ H, unsigned short* __restrict__ L){
  int t = blockIdx.x * 256 + threadIdx.x;
  if (t >= n) return;
  unsigned short h, l; splitbf(W[t], h, l);
  H[t] = h; L[t] = l;
}

// build combined UZ weights: rows [0,O) = W[:, :C]; rows [O,2O) = W[:, C:] - W[:, :C]; split hi/lo
__global__ __launch_bounds__(256) void k_make_wuz(const float* __restrict__ W, int O, int cshift,
    unsigned short* __restrict__ WH, unsigned short* __restrict__ WL){
  int C = 1 << cshift;
  int n = 2*O*C;
  int t = blockIdx.x * 256 + threadIdx.x;
  if (t >= n) return;
  int g = t >> cshift, c = t & (C - 1);
  int C2 = 2*C;
  float w;
  if (g < O) w = W[(size_t)g*C2 + c];
  else       w = W[(size_t)(g-O)*C2 + C + c] - W[(size_t)(g-O)*C2 + c];
  unsigned short h, l; splitbf(w, h, l);
  WH[t] = h; WL[t] = l;
}

// row norms from hi/lo planes (slice c0..c0+C of 512-wide rows)
__global__ __launch_bounds__(256) void k_norms_bf(const unsigned short* __restrict__ H,
    const unsigned short* __restrict__ L, int c0, int C, float* __restrict__ xx){
  int row = blockIdx.x * 256 + threadIdx.x;
  const unsigned short* h = H + (size_t)row*512 + c0;
  const unsigned short* l = L + (size_t)row*512 + c0;
  float a = 0.f;
  for (int c = 0; c < C; c += 8){
    bf16x8 vh = *(const bf16x8*)(h + c);
    bf16x8 vl = *(const bf16x8*)(l + c);
    #pragma unroll
    for (int j = 0; j < 8; ++j){
      float f = bf2f((unsigned short)vh[j]) + bf2f((unsigned short)vl[j]);
      a += f*f;
    }
  }
  xx[row] = a;
}

// ---------------- MFMA GEMM core (128x128 tile, BK=32, split-bf16 3-product) ----------------

__device__ __forceinline__ void stage_pair(unsigned short* dH, unsigned short* dL,
    const unsigned short* sH, const unsigned short* sL, int rowBase, int ld, int kOff, int tid){
  #pragma unroll
  for (int i = 0; i < 2; ++i){
    int q = tid + 256*i; int r = q >> 2; int kq = (q & 3) * 8;
    size_t go = (size_t)(rowBase + r)*ld + kOff + kq;
    *(bf16x8*)&dH[r*PITCH + kq] = *(const bf16x8*)(sH + go);
    *(bf16x8*)&dL[r*PITCH + kq] = *(const bf16x8*)(sL + go);
  }
}

__device__ __forceinline__ void mfma_step(const unsigned short* sAh, const unsigned short* sAl,
    const unsigned short* sBh, const unsigned short* sBl, int wm, int wn, int lane, f32x4 acc[4][4]){
  bf16x8 ah[4], al[4], bh[4], bl[4];
  int ko = (lane >> 4) * 8, li = lane & 15;
  #pragma unroll
  for (int i = 0; i < 4; ++i){
    ah[i] = *(const bf16x8*)&sAh[(wm + i*16 + li)*PITCH + ko];
    al[i] = *(const bf16x8*)&sAl[(wm + i*16 + li)*PITCH + ko];
    bh[i] = *(const bf16x8*)&sBh[(wn + i*16 + li)*PITCH + ko];
    bl[i] = *(const bf16x8*)&sBl[(wn + i*16 + li)*PITCH + ko];
  }
  #pragma unroll
  for (int mi = 0; mi < 4; ++mi){
    #pragma unroll
    for (int ni = 0; ni < 4; ++ni){
      acc[mi][ni] = __builtin_amdgcn_mfma_f32_16x16x32_bf16(ah[mi], bh[ni], acc[mi][ni], 0,0,0);
      acc[mi][ni] = __builtin_amdgcn_mfma_f32_16x16x32_bf16(ah[mi], bl[ni], acc[mi][ni], 0,0,0);
      acc[mi][ni] = __builtin_amdgcn_mfma_f32_16x16x32_bf16(al[mi], bh[ni], acc[mi][ni], 0,0,0);
    }
  }
}

// dist: D[z][n][m] = 2*<F[n],F[m]> - xx[n] - xx[m], F = (H+L) slice (ld 512), per-batch tiles
__global__ __launch_bounds__(256) void k_dist_mfma(const unsigned short* __restrict__ H,
    const unsigned short* __restrict__ L, int C, const float* __restrict__ xx,
    float* __restrict__ D, int b0){
  __shared__ unsigned short sAh[128*PITCH], sAl[128*PITCH], sBh[128*PITCH], sBl[128*PITCH];
  int b = b0 + blockIdx.z;
  int nb = blockIdx.y * 128, mb = blockIdx.x * 128;
  int rowA0 = b*2048 + nb, rowB0 = b*2048 + mb;
  int tid = threadIdx.x, lane = tid & 63, w = tid >> 6;
  int wm = (w >> 1) * 64, wn = (w & 1) * 64;
  f32x4 acc[4][4];
  #pragma unroll
  for (int i = 0; i < 4; ++i)
    #pragma unroll
    for (int j = 0; j < 4; ++j){ f32x4 z = {0.f,0.f,0.f,0.f}; acc[i][j] = z; }
  for (int kk = 0; kk < C; kk += 32){
    __syncthreads();
    stage_pair(sAh, sAl, H, L, rowA0, 512, kk, tid);
    stage_pair(sBh, sBl, H, L, rowB0, 512, kk, tid);
    __syncthreads();
    mfma_step(sAh, sAl, sBh, sBl, wm, wn, lane, acc);
  }
  int li = lane & 15, lq = lane >> 4;
  float xm[4];
  #pragma unroll
  for (int ni = 0; ni < 4; ++ni) xm[ni] = xx[rowB0 + wn + ni*16 + li];
  #pragma unroll
  for (int mi = 0; mi < 4; ++mi){
    #pragma unroll
    for (int v = 0; v < 4; ++v){
      int row = wm + mi*16 + lq*4 + v;
      float xn = xx[rowA0 + row];
      size_t base = ((size_t)(blockIdx.z*2048 + nb + row))*2048 + mb;
      #pragma unroll
      for (int ni = 0; ni < 4; ++ni){
        D[base + wn + ni*16 + li] = 2.f*acc[mi][ni][v] - xn - xm[ni];
      }
    }
  }
}

// uz: UZ[row][g] = <F[row], WUZ[g]> (fp32 out), F slice ld 512, WUZ ld C
__global__ __launch_bounds__(256) void k_uz_mfma(const unsigned short* __restrict__ H,
    const unsigned short* __restrict__ L, int C,
    const unsigned short* __restrict__ WH, const unsigned short* __restrict__ WL,
    int N2, float* __restrict__ UZ){
  __shared__ unsigned short sAh[128*PITCH], sAl[128*PITCH], sBh[128*PITCH], sBl[128*PITCH];
  int rows0 = blockIdx.x * 128;
  int ob = blockIdx.y * 128;
  int tid = threadIdx.x, lane = tid & 63, w = tid >> 6;
  int wm = (w >> 1) * 64, wn = (w & 1) * 64;
  f32x4 acc[4][4];
  #pragma unroll
  for (int i = 0; i < 4; ++i)
    #pragma unroll
    for (int j = 0; j < 4; ++j){ f32x4 z = {0.f,0.f,0.f,0.f}; acc[i][j] = z; }
  for (int kk = 0; kk < C; kk += 32){
    __syncthreads();
    stage_pair(sAh, sAl, H, L, rows0, 512, kk, tid);
    stage_pair(sBh, sBl, WH, WL, ob, C, kk, tid);
    __syncthreads();
    mfma_step(sAh, sAl, sBh, sBl, wm, wn, lane, acc);
  }
  int li = lane & 15, lq = lane >> 4;
  #pragma unroll
  for (int mi = 0; mi < 4; ++mi){
    #pragma unroll
    for (int v = 0; v < 4; ++v){
      int row = rows0 + wm + mi*16 + lq*4 + v;
      size_t base = (size_t)row * N2 + ob;
      #pragma unroll
      for (int ni = 0; ni < 4; ++ni) UZ[base + wn + ni*16 + li] = acc[mi][ni][v];
    }
  }
}

// conv5: A = XCH/XCL (32768x512), B = W5 split (1024x512); fused bn/lrelu + max/sum over 128-pt tile
__global__ __launch_bounds__(256) void k_conv5_mfma(const unsigned short* __restrict__ XH,
    const unsigned short* __restrict__ XL, const unsigned short* __restrict__ WH,
    const unsigned short* __restrict__ WL, const float* __restrict__ g5, const float* __restrict__ b5,
    float* __restrict__ pmax, float* __restrict__ psum){
  __shared__ unsigned short sAh[128*PITCH], sAl[128*PITCH], sBh[128*PITCH], sBl[128*PITCH];
  __shared__ float redm[2][128];
  __shared__ float reds[2][128];
  int bx = blockIdx.x;
  int b = bx >> 4, nt = bx & 15;
  int ob = blockIdx.y * 128;
  int rowA0 = b*2048 + nt*128;
  int tid = threadIdx.x, lane = tid & 63, w = tid >> 6;
  int wm = (w >> 1) * 64, wn = (w & 1) * 64, wy = w >> 1, wx = w & 1;
  f32x4 acc[4][4];
  #pragma unroll
  for (int i = 0; i < 4; ++i)
    #pragma unroll
    for (int j = 0; j < 4; ++j){ f32x4 z = {0.f,0.f,0.f,0.f}; acc[i][j] = z; }
  for (int kk = 0; kk < 512; kk += 32){
    __syncthreads();
    stage_pair(sAh, sAl, XH, XL, rowA0, 512, kk, tid);
    stage_pair(sBh, sBl, WH, WL, ob, 512, kk, tid);
    __syncthreads();
    mfma_step(sAh, sAl, sBh, sBl, wm, wn, lane, acc);
  }
  int li = lane & 15;
  #pragma unroll
  for (int ni = 0; ni < 4; ++ni){
    int c = ob + wn + ni*16 + li;
    float s = g5[c] * RSQ, bb = b5[c];
    float m = -INFINITY, sm = 0.f;
    #pragma unroll
    for (int mi = 0; mi < 4; ++mi){
      #pragma unroll
      for (int v = 0; v < 4; ++v){
        float y = lrelu_f(s*acc[mi][ni][v] + bb);
        m = fmaxf(m, y);
        sm += y;
      }
    }
    m = fmaxf(m, __shfl_xor(m, 16)); m = fmaxf(m, __shfl_xor(m, 32));
    sm += __shfl_xor(sm, 16); sm += __shfl_xor(sm, 32);
    if (lane < 16){
      redm[wy][wx*64 + ni*16 + li] = m;
      reds[wy][wx*64 + ni*16 + li] = sm;
    }
  }
  __syncthreads();
  if (tid < 128){
    float m = fmaxf(redm[0][tid], redm[1][tid]);
    float s = reds[0][tid] + reds[1][tid];
    size_t pi = (size_t)(b*16 + nt)*1024 + ob + tid;
    pmax[pi] = m;
    psum[pi] = s;
  }
}

// ---------------- fp32 kernels for block 0 (C=3) ----------------

__global__ __launch_bounds__(256) void k_dist3(const float* __restrict__ F0, float* __restrict__ D, int b0){
  __shared__ float sa[3][128];
  __shared__ float sb[3][128];
  int b = b0 + blockIdx.z;
  int nb = blockIdx.y * 128, mb = blockIdx.x * 128;
  int tid = threadIdx.x, tx = tid & 15, ty = tid >> 4;
  if (tid < 128){
    int r = tid;
    const float* p = F0 + (size_t)(b*2048 + nb + r)*3;
    sa[0][r] = p[0]; sa[1][r] = p[1]; sa[2][r] = p[2];
  } else {
    int r = tid - 128;
    const float* p = F0 + (size_t)(b*2048 + mb + r)*3;
    sb[0][r] = p[0]; sb[1][r] = p[1]; sb[2][r] = p[2];
  }
  __syncthreads();
  float ax[8], ay[8], az[8], bx[8], by[8], bz[8];
  #pragma unroll
  for (int i=0;i<8;i++){
    int ri = (i<4) ? 4*ty+i : 64 + 4*ty + (i-4);
    ax[i] = sa[0][ri]; ay[i] = sa[1][ri]; az[i] = sa[2][ri];
    int cj = (i<4) ? 4*tx+i : 64 + 4*tx + (i-4);
    bx[i] = sb[0][cj]; by[i] = sb[1][cj]; bz[i] = sb[2][cj];
  }
  #pragma unroll
  for (int i=0;i<8;i++){
    int ri = (i<4) ? 4*ty+i : 64 + 4*ty + (i-4);
    size_t base = ((size_t)(blockIdx.z*2048 + nb + ri))*2048 + mb;
    float v[8];
    #pragma unroll
    for (int j=0;j<8;j++){
      float dx = ax[i]-bx[j], dy = ay[i]-by[j], dz = az[i]-bz[j];
      v[j] = -(dx*dx + dy*dy + dz*dz);
    }
    *(float4*)&D[base + 4*tx]      = make_float4(v[0],v[1],v[2],v[3]);
    *(float4*)&D[base + 64 + 4*tx] = make_float4(v[4],v[5],v[6],v[7]);
  }
}

#define GEMM_STEP(KK) { \
      float a[8], wv_[8]; \
      *(float4*)&a[0] = *(const float4*)&As[(KK)*LDL + 4*ty]; \
      *(float4*)&a[4] = *(const float4*)&As[(KK)*LDL + 64 + 4*ty]; \
      *(float4*)&wv_[0] = *(const float4*)&Bs[(KK)*LDL + 4*tx]; \
      *(float4*)&wv_[4] = *(const float4*)&Bs[(KK)*LDL + 64 + 4*tx]; \
      _Pragma("unroll") \
      for (int i_ = 0; i_ < 8; ++i_){ \
        _Pragma("unroll") \
        for (int j_ = 0; j_ < 8; ++j_) acc[i_][j_] += a[i_]*wv_[j_]; \
      } }

// fp32 uz for block 0 (C=3): UZ[row][0:O]=F.Wd^T, UZ[row][O:2O]=F.(Wc-Wd)^T
__global__ __launch_bounds__(256) void k_uz(const float* __restrict__ F, int ldF, int C,
    const float* __restrict__ W, int O, float* __restrict__ UZ){
  __shared__ float As[32*LDL];
  __shared__ float Bs[32*LDL];
  int N2 = 2*O, C2 = 2*C;
  int rows0 = blockIdx.x * 128;
  int ob = blockIdx.y * 128;
  int tid = threadIdx.x, tx = tid & 15, ty = tid >> 4;
  float acc[8][8] = {};
  for (int cc = 0; cc < C; cc += 32){
    int kc = C - cc; if (kc > 32) kc = 32;
    __syncthreads();
    for (int t = tid; t < 128*32; t += 256){
      int r = t >> 5, k = t & 31;
      if (k < kc){
        As[k*LDL + r] = F[(size_t)(rows0 + r)*ldF + cc + k];
        int g = ob + r; float wv;
        if (g < O) wv = W[(size_t)g*C2 + cc + k];
        else       wv = W[(size_t)(g-O)*C2 + C + cc + k] - W[(size_t)(g-O)*C2 + cc + k];
        Bs[k*LDL + r] = wv;
      }
    }
    __syncthreads();
    for (int k = 0; k < kc; ++k) GEMM_STEP(k)
  }
  #pragma unroll
  for (int i=0;i<8;i++){
    int ri = (i<4) ? 4*ty+i : 64 + 4*ty + (i-4);
    size_t base = (size_t)(rows0 + ri)*N2 + ob;
    *(float4*)&UZ[base + 4*tx]      = make_float4(acc[i][0],acc[i][1],acc[i][2],acc[i][3]);
    *(float4*)&UZ[base + 64 + 4*tx] = make_float4(acc[i][4],acc[i][5],acc[i][6],acc[i][7]);
  }
}

// ---------------- kNN select / aggregate / pool / fc ----------------

// top-20 per row: threshold (20th-largest lane-max via bitonic) + ballot-compaction + final bitonic.
// float4 row loads; lane owns indices {j*256 + lane*4 + t}. Threshold bound is partition-independent.
__global__ __launch_bounds__(256) void k_knn_select(const float* __restrict__ D, int* __restrict__ idxo, int b0){
  __shared__ unsigned long long cand[4][64];
  int g = blockIdx.y; int b = b0 + g;
  int w = threadIdx.x >> 6, lane = threadIdx.x & 63;
  int r = blockIdx.x*4 + w;
  const float* Drow = D + ((size_t)(g*2048 + r))*2048;
  float vals[32];
  unsigned long long kmax = 0ull;
  #pragma unroll
  for (int j=0;j<8;j++){
    float4 v4 = *(const float4*)(Drow + j*256 + lane*4);
    int m0 = j*256 + lane*4;
    vals[j*4+0]=v4.x; vals[j*4+1]=v4.y; vals[j*4+2]=v4.z; vals[j*4+3]=v4.w;
    unsigned long long e;
    e = packkey(v4.x, m0+0); if (e > kmax) kmax = e;
    e = packkey(v4.y, m0+1); if (e > kmax) kmax = e;
    e = packkey(v4.z, m0+2); if (e > kmax) kmax = e;
    e = packkey(v4.w, m0+3); if (e > kmax) kmax = e;
  }
  // 20th largest of the 64 lane-maxes (ascending sort -> index 44); provable lower bound on true t20
  unsigned long long srt = bitonic64_asc(kmax, lane);
  unsigned long long t = __shfl(srt, 44);
  // compact keys >= t
  unsigned long long ltmask = (1ull << lane) - 1ull;
  int base = 0;
  #pragma unroll
  for (int s=0;s<32;s++){
    int m = (s >> 2)*256 + lane*4 + (s & 3);
    unsigned long long ke = packkey(vals[s], m);
    bool pred = ke >= t;
    unsigned long long mask = __ballot(pred);
    int pos = base + __popcll(mask & ltmask);
    if (pred && pos < 64) cand[w][pos] = ke;
    base += __popcll(mask);
  }
  int* op = idxo + (size_t)(b*2048 + r)*20;
  if (base <= 64){
    unsigned long long ck = (lane < base) ? cand[w][lane] : 0ull;
    ck = bitonic64_asc(ck, lane);
    if (lane >= 44) op[63 - lane] = 2047 - (int)(ck & 0xFFFFFFFFull);
  } else {
    // fallback: lazy iterative argmax (rare, correctness guarantee)
    unsigned long long k1 = 0ull, k2 = 0ull;
    #pragma unroll
    for (int s=0;s<32;s++){
      int m = (s >> 2)*256 + lane*4 + (s & 3);
      unsigned long long ke = packkey(vals[s], m);
      if (ke > k1){ k2 = k1; k1 = ke; }
      else if (ke > k2){ k2 = ke; }
    }
    unsigned int removed = 0u;
    for (int it = 0; it < 20; ++it){
      unsigned long long km = k1;
      #pragma unroll
      for (int off = 1; off < 64; off <<= 1){
        unsigned long long o2 = __shfl_xor(km, off);
        if (o2 > km) km = o2;
      }
      int bi = 2047 - (int)(km & 0xFFFFFFFFull);
      if (lane == 0) op[it] = bi;
      if (km == k1){
        removed |= 1u << (((bi >> 8) << 2) | (bi & 3));
        if (k2 != 0ull){ k1 = k2; k2 = 0ull; }
        else {
          unsigned long long b1 = 0ull, b2 = 0ull;
          #pragma unroll
          for (int s=0;s<32;s++){
            if (!((removed >> s) & 1u)){
              int m = (s >> 2)*256 + lane*4 + (s & 3);
              unsigned long long ke = packkey(vals[s], m);
              if (ke > b1){ b2 = b1; b1 = ke; }
              else if (ke > b2){ b2 = ke; }
            }
          }
          k1 = b1; k2 = b2;
        }
      }
    }
  }
}

// out(point,o..o+3) = lrelu(bn( max_j UZ[nbr_j][o] + UZ[point][O+o] )) -> hi/lo bf16 planes
// blockIdx swizzled so batch == (blockIdx & 7)-affine -> per-XCD L2 sees ~2 batch slabs
__global__ __launch_bounds__(256) void k_aggregate(const float* __restrict__ UZ,
    const int* __restrict__ idx, const float* __restrict__ gam, const float* __restrict__ bet,
    int oshift, unsigned short* __restrict__ outH, unsigned short* __restrict__ outL){
  int O = 1 << oshift;
  int ogshift = oshift - 2;           // float4 groups per point = O/4
  int tid = threadIdx.x;
  // XCD batch-locality swizzle: bijection on [0, gridDim.x)
  int NBB = gridDim.x >> 4;           // blocks per batch
  int g = blockIdx.x;
  int q = g >> 3, xq = g & 7;
  int hi = (q >= NBB) ? 1 : 0;
  int within = q - NBB*hi;
  int batch = xq + 8*hi;
  int pblock = batch * NBB + within;
  int point = pblock * (256 >> ogshift) + (tid >> ogshift);
  int o = (tid & ((O >> 2) - 1)) << 2;
  int N2 = 2*O;
  int b = point >> 11;
  const int* ip = idx + (size_t)point * 20;
  float4 mv = make_float4(-INFINITY,-INFINITY,-INFINITY,-INFINITY);
  #pragma unroll
  for (int j = 0; j < 20; ++j){
    int m = ip[j];
    float4 v = *(const float4*)(UZ + (size_t)((b << 11) + m)*N2 + o);
    mv.x = fmaxf(mv.x, v.x); mv.y = fmaxf(mv.y, v.y);
    mv.z = fmaxf(mv.z, v.z); mv.w = fmaxf(mv.w, v.w);
  }
  float4 z = *(const float4*)(UZ + (size_t)point*N2 + O + o);
  float s0 = gam[o+0]*RSQ, s1 = gam[o+1]*RSQ, s2 = gam[o+2]*RSQ, s3 = gam[o+3]*RSQ;
  float y0 = lrelu_f(s0*(mv.x + z.x) + bet[o+0]);
  float y1 = lrelu_f(s1*(mv.y + z.y) + bet[o+1]);
  float y2 = lrelu_f(s2*(mv.z + z.z) + bet[o+2]);
  float y3 = lrelu_f(s3*(mv.w + z.w) + bet[o+3]);
  ushort4 hh, ll;
  splitbf(y0, hh.x, ll.x); splitbf(y1, hh.y, ll.y);
  splitbf(y2, hh.z, ll.z); splitbf(y3, hh.w, ll.w);
  *(ushort4*)&outH[(size_t)point*512 + o] = hh;
  *(ushort4*)&outL[(size_t)point*512 + o] = ll;
}

__global__ __launch_bounds__(256) void k_pool(const float* __restrict__ pmax, const float* __restrict__ psum,
    float* __restrict__ p){
  int t = blockIdx.x * 256 + threadIdx.x; // 16384
  int b = t >> 10, o = t & 1023;
  float m = -INFINITY, s = 0.f;
  for (int nt = 0; nt < 16; ++nt){
    size_t pi = (size_t)(b*16 + nt)*1024 + o;
    m = fmaxf(m, pmax[pi]);
    s += psum[pi];
  }
  p[(size_t)b*2048 + o] = m;
  p[(size_t)b*2048 + 1024 + o] = s * (1.f/2048.f);
}

// ---------- grid-parallel FC head ----------
__global__ __launch_bounds__(256) void k_fc1(const float* __restrict__ p, const float* __restrict__ L1w,
    const float* __restrict__ g6, const float* __restrict__ b6, float* __restrict__ h1){
  int o = blockIdx.x;
  int tid = threadIdx.x, lane = tid & 63, w = tid >> 6;
  int k0 = w*512 + lane*8;
  const float4* wp = (const float4*)(L1w + (size_t)o*2048 + k0);
  float4 w0 = wp[0], w1 = wp[1];
  __shared__ float part[4][16];
  for (int b = 0; b < 16; ++b){
    const float4* pp = (const float4*)(p + (size_t)b*2048 + k0);
    float4 p0 = pp[0], p1 = pp[1];
    float a = p0.x*w0.x + p0.y*w0.y + p0.z*w0.z + p0.w*w0.w
            + p1.x*w1.x + p1.y*w1.y + p1.z*w1.z + p1.w*w1.w;
    #pragma unroll
    for (int off = 32; off >= 1; off >>= 1) a += __shfl_down(a, off);
    if (lane == 0) part[w][b] = a;
  }
  __syncthreads();
  if (tid < 16){
    float a = part[0][tid] + part[1][tid] + part[2][tid] + part[3][tid];
    h1[(size_t)tid*512 + o] = lrelu_f(g6[o]*RSQ*a + b6[o]);
  }
}

__global__ __launch_bounds__(256) void k_fc2(const float* __restrict__ h1, const float* __restrict__ L2w,
    const float* __restrict__ L2b, const float* __restrict__ g7, const float* __restrict__ b7,
    float* __restrict__ h2){
  int o = blockIdx.x;
  int tid = threadIdx.x, lane = tid & 63, w = tid >> 6;
  int k0 = w*128 + lane*2;
  float2 wv = *(const float2*)(L2w + (size_t)o*512 + k0);
  __shared__ float part[4][16];
  for (int b = 0; b < 16; ++b){
    float2 hv = *(const float2*)(h1 + (size_t)b*512 + k0);
    float a = hv.x*wv.x + hv.y*wv.y;
    #pragma unroll
    for (int off = 32; off >= 1; off >>= 1) a += __shfl_down(a, off);
    if (lane == 0) part[w][b] = a;
  }
  __syncthreads();
  if (tid < 16){
    float a = part[0][tid] + part[1][tid] + part[2][tid] + part[3][tid] + L2b[o];
    h2[(size_t)tid*256 + o] = lrelu_f(g7[o]*RSQ*a + b7[o]);
  }
}

__global__ __launch_bounds__(256) void k_fc3(const float* __restrict__ h2, const float* __restrict__ L3w,
    const float* __restrict__ L3b, float* __restrict__ out){
  int o = blockIdx.x;
  int tid = threadIdx.x, lane = tid & 63, w = tid >> 6;
  int k0 = w*64 + lane;
  float wv = L3w[(size_t)o*256 + k0];
  __shared__ float part[4][16];
  for (int b = 0; b < 16; ++b){
    float a = h2[(size_t)b*256 + k0] * wv;
    #pragma unroll
    for (int off = 32; off >= 1; off >>= 1) a += __shfl_down(a, off);
    if (lane == 0) part[w][b] = a;
  }
  __syncthreads();
  if (tid < 16){
    float a = part[0][tid] + part[1][tid] + part[2][tid] + part[3][tid] + L3b[o];
    out[(size_t)tid*40 + o] = a;
  }
}

extern "C" void kernel_launch(void* const* d_in, const int* in_sizes, int n_in,
                              void* d_out, int out_size, void* d_ws, size_t ws_size,
                              hipStream_t stream) {
  (void)in_sizes; (void)n_in; (void)out_size;
  const float* x   = (const float*)d_in[0];
  const float* W1  = (const float*)d_in[1];
  const float* W2  = (const float*)d_in[2];
  const float* W3  = (const float*)d_in[3];
  const float* W4  = (const float*)d_in[4];
  const float* W5  = (const float*)d_in[5];
  const float* g1  = (const float*)d_in[6];   const float* b1  = (const float*)d_in[7];
  const float* g2  = (const float*)d_in[8];   const float* b2  = (const float*)d_in[9];
  const float* g3  = (const float*)d_in[10];  const float* b3  = (const float*)d_in[11];
  const float* g4  = (const float*)d_in[12];  const float* b4  = (const float*)d_in[13];
  const float* g5  = (const float*)d_in[14];  const float* b5  = (const float*)d_in[15];
  const float* g6  = (const float*)d_in[16];  const float* b6  = (const float*)d_in[17];
  const float* g7  = (const float*)d_in[18];  const float* b7  = (const float*)d_in[19];
  const float* L1w = (const float*)d_in[20];
  const float* L2w = (const float*)d_in[21];  const float* L2b = (const float*)d_in[22];
  const float* L3w = (const float*)d_in[23];  const float* L3b = (const float*)d_in[24];
  float* out = (float*)d_out;

  char* ws = (char*)d_ws;
  size_t off = 0;
  auto alloc = [&](size_t nbytes) -> void* {
    void* pp = (void*)(ws + off);
    off += (nbytes + 255) & ~(size_t)255;
    return pp;
  };
  float*          F0   = (float*)alloc(98304ull * 4);
  unsigned short* XCH  = (unsigned short*)alloc(16777216ull * 2);
  unsigned short* XCL  = (unsigned short*)alloc(16777216ull * 2);
  float*          UZ   = (float*)alloc(16777216ull * 4);
  float*          XX   = (float*)alloc(32768ull * 4);
  int*            IDX  = (int*)alloc(655360ull * 4);
  float*          PM   = (float*)alloc(262144ull * 4);
  float*          PS   = (float*)alloc(262144ull * 4);
  float*          P    = (float*)alloc(32768ull * 4);
  float*          H1   = (float*)alloc(8192ull * 4);
  float*          H2   = (float*)alloc(4096ull * 4);
  unsigned short* W5H  = (unsigned short*)alloc(524288ull * 2);
  unsigned short* W5L  = (unsigned short*)alloc(524288ull * 2);
  unsigned short* WUZH = (unsigned short*)alloc(65536ull * 2);
  unsigned short* WUZL = (unsigned short*)alloc(65536ull * 2);
  const size_t dbytes = 2048ull * 2048ull * 4ull;           // one batch of D
  size_t rem = (ws_size > off) ? (ws_size - off) : 0;
  int G = (int)(rem / dbytes);
  if (G > 8) G = 8;   // keep D chunk (<=128 MB) L3-resident between dist write and knn read
  if (G < 1) G = 1;
  float* Dbuf = (float*)(ws + off);

  k_transpose<<<dim3(384), dim3(256), 0, stream>>>(x, F0);
  k_split_plain<<<dim3(2048), dim3(256), 0, stream>>>(W5, 524288, W5H, W5L);

  struct Blk { int c0; int C; int cshift; const float* W; const float* g; const float* bb; int O; int oshift; int c0out; };
  Blk cfg[4] = {
    { 0,   3,   0, W1, g1, b1, 64,  6, 0   },   // block 0 special (fp32 path)
    { 0,   64,  6, W2, g2, b2, 64,  6, 64  },
    { 64,  64,  6, W3, g3, b3, 128, 7, 128 },
    { 128, 128, 7, W4, g4, b4, 256, 8, 256 },
  };

  for (int blk = 0; blk < 4; ++blk){
    const Blk& c = cfg[blk];
    if (blk > 0){
      k_make_wuz<<<dim3((2*c.O*c.C + 255)/256), dim3(256), 0, stream>>>(c.W, c.O, c.cshift, WUZH, WUZL);
      k_norms_bf<<<dim3(128), dim3(256), 0, stream>>>(XCH, XCL, c.c0, c.C, XX);
    }
    for (int b0 = 0; b0 < 16; b0 += G){
      int Gc = 16 - b0; if (Gc > G) Gc = G;
      if (blk == 0)
        k_dist3<<<dim3(16, 16, Gc), dim3(256), 0, stream>>>(F0, Dbuf, b0);
      else
        k_dist_mfma<<<dim3(16, 16, Gc), dim3(256), 0, stream>>>(XCH + c.c0, XCL + c.c0, c.C, XX, Dbuf, b0);
      k_knn_select<<<dim3(512, Gc), dim3(256), 0, stream>>>(Dbuf, IDX, b0);
    }
    if (blk == 0)
      k_uz<<<dim3(256, 1), dim3(256), 0, stream>>>(F0, 3, 3, c.W, c.O, UZ);
    else
      k_uz_mfma<<<dim3(256, (2*c.O)/128), dim3(256), 0, stream>>>(XCH + c.c0, XCL + c.c0, c.C, WUZH, WUZL, 2*c.O, UZ);
    k_aggregate<<<dim3(32768 >> (8 - (c.oshift - 2))), dim3(256), 0, stream>>>(UZ, IDX, c.g, c.bb, c.oshift,
                                                                         XCH + c.c0out, XCL + c.c0out);
  }

  k_conv5_mfma<<<dim3(256, 8), dim3(256), 0, stream>>>(XCH, XCL, W5H, W5L, g5, b5, PM, PS);
  k_pool<<<dim3(64), dim3(256), 0, stream>>>(PM, PS, P);
  k_fc1<<<dim3(512), dim3(256), 0, stream>>>(P, L1w, g6, b6, H1);
  k_fc2<<<dim3(256), dim3(256), 0, stream>>>(H1, L2w, L2b, g7, b7, H2);
  k_fc3<<<dim3(40),  dim3(256), 0, stream>>>(H2, L3w, L3b, out);
}